// Round 7
// baseline (374.140 us; speedup 1.0000x reference)
//
#include <hip/hip_runtime.h>
#include <stdint.h>

typedef unsigned short u16;
typedef uint32_t u32;
typedef __bf16 bf16x8 __attribute__((ext_vector_type(8)));
typedef float f32x4 __attribute__((ext_vector_type(4)));

__device__ __forceinline__ u16 f2bf(float f) {
    u32 u = __builtin_bit_cast(u32, f);
    u += 0x7fffu + ((u >> 16) & 1u);   // RTNE
    return (u16)(u >> 16);
}

__device__ __forceinline__ f32x4 mfma16(bf16x8 a, bf16x8 b, f32x4 c) {
    return __builtin_amdgcn_mfma_f32_16x16x32_bf16(a, b, c, 0, 0, 0);
}

__device__ __forceinline__ void gld_lds16(void* lds, const void* g) {
    __builtin_amdgcn_global_load_lds(
        (__attribute__((address_space(1))) void*)(uintptr_t)g,
        (__attribute__((address_space(3))) void*)(u32)(uintptr_t)lds,
        16, 0, 0);
}

// ---------------- normalize rows of X, cast to bf16 ----------------
__global__ __launch_bounds__(256) void k_norm(const float* __restrict__ X,
                                              u16* __restrict__ Xn) {
    const int row = blockIdx.x;
    const float4 v = ((const float4*)(X + (size_t)row * 1024))[threadIdx.x];
    float ss = v.x * v.x + v.y * v.y + v.z * v.z + v.w * v.w;
#pragma unroll
    for (int m = 1; m < 64; m <<= 1) ss += __shfl_xor(ss, m);
    __shared__ float red[4];
    if ((threadIdx.x & 63) == 0) red[threadIdx.x >> 6] = ss;
    __syncthreads();
    const float sc = 1.0f / sqrtf(red[0] + red[1] + red[2] + red[3]);
    ushort4 o;
    o.x = f2bf(v.x * sc); o.y = f2bf(v.y * sc);
    o.z = f2bf(v.z * sc); o.w = f2bf(v.w * sc);
    ((ushort4*)(Xn + (size_t)row * 1024))[threadIdx.x] = o;
}

// ---------------- fp32 -> bf16 transposing cast, 64x64 tiles ----------------
__global__ __launch_bounds__(256) void k_transpose_cast64(
    const float* __restrict__ src, u16* __restrict__ dst,
    int R, int rstride, long zsrc, long zdst) {
    __shared__ float tile[64][65];
    src += (size_t)blockIdx.z * zsrc;
    dst += (size_t)blockIdx.z * zdst;
    const int c0 = blockIdx.x * 64, r0 = blockIdx.y * 64;
    const int tid = threadIdx.x;
    const int lr = tid >> 4, lc = tid & 15;
#pragma unroll
    for (int i = 0; i < 4; ++i) {
        const int r = lr + i * 16;
        const float4 v = *(const float4*)(src + (size_t)(r0 + r) * rstride + c0 + lc * 4);
        tile[r][lc * 4 + 0] = v.x; tile[r][lc * 4 + 1] = v.y;
        tile[r][lc * 4 + 2] = v.z; tile[r][lc * 4 + 3] = v.w;
    }
    __syncthreads();
    const int c = tid >> 2, seg = tid & 3;
    u32 w[8];
#pragma unroll
    for (int j = 0; j < 8; ++j) {
        const u32 lo = f2bf(tile[seg * 16 + 2 * j][c]);
        const u32 hi = f2bf(tile[seg * 16 + 2 * j + 1][c]);
        w[j] = lo | (hi << 16);
    }
    u16* dp = dst + (size_t)(c0 + c) * R + r0 + seg * 16;
    uint4 q0; q0.x = w[0]; q0.y = w[1]; q0.z = w[2]; q0.w = w[3];
    uint4 q1; q1.x = w[4]; q1.y = w[5]; q1.z = w[6]; q1.w = w[7];
    *(uint4*)dp = q0;
    *((uint4*)dp + 1) = q1;
}

// ============ 256x256 8-phase GEMM core, pipelined ds_reads ============
#define G8_PRE(Aptr, Bptr)                                                       \
    const int tid = threadIdx.x, lane = tid & 63;                                \
    const int wid = tid >> 6, wm = wid >> 2, wn = wid & 3;                       \
    const int cl = lane & 15, g = lane >> 4;                                     \
    const int colb = (tid & 7) * 16;                                             \
    const int scb = colb ^ (((tid >> 3) & 7) << 4);                              \
    const int rbA = ((tid >> 3) & 31) + ((tid >> 8) << 7);                       \
    const int rbB = tid >> 3;                                                    \
    const char* gA = (const char*)(Aptr) + (size_t)(m0 + rbA) * 2048 + scb;      \
    const char* gB = (const char*)(Bptr) + (size_t)(n0 + rbB) * 2048 + scb;      \
    const u32 lA = (u32)(rbA * 128 + colb);                                      \
    const u32 lB = (u32)(65536 + rbB * 128 + colb);                              \
    const int xr0 = (g * 16) ^ ((cl & 7) << 4);                                  \
    const int xr1 = (64 + g * 16) ^ ((cl & 7) << 4);

#define G8_STA(q, tau, beta) gld_lds16(sm + (beta) + lA + (q) * 4096,            \
                                       gA + (q) * 65536 + (size_t)(tau) * 128);
#define G8_STB(c, tau, beta) gld_lds16(sm + (beta) + lB + (c) * 8192,            \
                                       gB + (c) * 131072 + (size_t)(tau) * 128);

#define G8_RDB(beta)                                                             \
    _Pragma("unroll") for (int nf = 0; nf < 4; ++nf) {                           \
        const u32 rb_ = (beta) + 65536 + (u32)(wn * 64 + nf * 16 + cl) * 128;    \
        bF[nf][0] = *(const bf16x8*)(sm + rb_ + xr0);                            \
        bF[nf][1] = *(const bf16x8*)(sm + rb_ + xr1);                            \
    }
#define G8_RDA2(dst, q, beta)                                                    \
    _Pragma("unroll") for (int m = 0; m < 2; ++m) {                              \
        const u32 ra_ = (beta) + (u32)(wm * 128 + (q) * 32 + m * 16 + cl) * 128; \
        dst[m][0] = *(const bf16x8*)(sm + ra_ + xr0);                            \
        dst[m][1] = *(const bf16x8*)(sm + ra_ + xr1);                            \
    }

#define G8_WAIT4 asm volatile("s_waitcnt lgkmcnt(4)" ::: "memory");              \
    __builtin_amdgcn_sched_barrier(0);
#define G8_WAIT0 asm volatile("s_waitcnt lgkmcnt(0)" ::: "memory");              \
    __builtin_amdgcn_sched_barrier(0);

#define G8_MMA(q, SRC)                                                           \
    __builtin_amdgcn_s_setprio(1);                                               \
    _Pragma("unroll") for (int m = 0; m < 2; ++m)                                \
        _Pragma("unroll") for (int nf = 0; nf < 4; ++nf) {                       \
            acc[(q)*2 + m][nf] = mfma16(SRC[m][0], bF[nf][0], acc[(q)*2 + m][nf]);\
            acc[(q)*2 + m][nf] = mfma16(SRC[m][1], bF[nf][1], acc[(q)*2 + m][nf]);\
        }                                                                        \
    __builtin_amdgcn_s_setprio(0);                                               \
    __builtin_amdgcn_s_barrier();                                                \
    __builtin_amdgcn_sched_barrier(0);

#define G8_LOOP                                                                  \
    bf16x8 aFe[2][2], aFo[2][2], bF[4][2];                                       \
    G8_STA(0, 0, 0) G8_STB(0, 0, 0) G8_STA(1, 0, 0) G8_STB(1, 0, 0)              \
    G8_STA(2, 0, 0) G8_STB(2, 0, 0) G8_STA(3, 0, 0) G8_STB(3, 0, 0)              \
    G8_STA(0, 1, 32768) G8_STB(0, 1, 32768)                                      \
    G8_STA(1, 1, 32768) G8_STB(1, 1, 32768)                                      \
    G8_STA(2, 1, 32768) G8_STB(2, 1, 32768)                                      \
    for (int it = 0; it < 8; ++it) {                                             \
        const int t1 = 2 * it + 1, t2v = 2 * it + 2, t3v = 2 * it + 3;           \
        const bool nt = (it < 7);                                                \
        /* p1 */                                                                 \
        G8_STA(3, t1, 32768) G8_STB(3, t1, 32768)                                \
        asm volatile("s_waitcnt vmcnt(8)" ::: "memory");                         \
        __builtin_amdgcn_s_barrier();                                            \
        G8_RDB(0) G8_RDA2(aFe, 0, 0) G8_RDA2(aFo, 1, 0)                          \
        G8_WAIT4 G8_MMA(0, aFe)                                                  \
        /* p2 */                                                                 \
        if (nt) { G8_STA(0, t2v, 0) G8_STB(0, t2v, 0) }                          \
        G8_RDA2(aFe, 2, 0)                                                       \
        G8_WAIT4 G8_MMA(1, aFo)                                                  \
        /* p3 */                                                                 \
        if (nt) { G8_STA(1, t2v, 0) G8_STB(1, t2v, 0) }                          \
        G8_RDA2(aFo, 3, 0)                                                       \
        G8_WAIT4 G8_MMA(2, aFe)                                                  \
        /* p4 */                                                                 \
        if (nt) { G8_STA(2, t2v, 0) G8_STB(2, t2v, 0) }                          \
        G8_WAIT0 G8_MMA(3, aFo)                                                  \
        /* p5 */                                                                 \
        if (nt) {                                                                \
            G8_STA(3, t2v, 0) G8_STB(3, t2v, 0)                                  \
            asm volatile("s_waitcnt vmcnt(8)" ::: "memory");                     \
        } else {                                                                 \
            asm volatile("s_waitcnt vmcnt(0)" ::: "memory");                     \
        }                                                                        \
        __builtin_amdgcn_s_barrier();                                            \
        G8_RDB(32768) G8_RDA2(aFe, 0, 32768) G8_RDA2(aFo, 1, 32768)              \
        G8_WAIT4 G8_MMA(0, aFe)                                                  \
        /* p6 */                                                                 \
        if (nt) { G8_STA(0, t3v, 32768) G8_STB(0, t3v, 32768) }                  \
        G8_RDA2(aFe, 2, 32768)                                                   \
        G8_WAIT4 G8_MMA(1, aFo)                                                  \
        /* p7 */                                                                 \
        if (nt) { G8_STA(1, t3v, 32768) G8_STB(1, t3v, 32768) }                  \
        G8_RDA2(aFo, 3, 32768)                                                   \
        G8_WAIT4 G8_MMA(2, aFe)                                                  \
        /* p8 */                                                                 \
        if (nt) { G8_STA(2, t3v, 32768) G8_STB(2, t3v, 32768) }                  \
        G8_WAIT0 G8_MMA(3, aFo)                                                  \
    }

// ---------------- QKV GEMM: Xn[16384x1024] @ Wt^T ----------------
__global__ __launch_bounds__(512, 2) void k_gemm_qkv(
    const u16* __restrict__ A, const u16* __restrict__ Bt,
    const float* __restrict__ bias,
    u16* __restrict__ Qo, u16* __restrict__ Kt, u16* __restrict__ Vt) {
    __shared__ __align__(16) char sm[131072];
    u32 bid = blockIdx.x;                      // 768 blocks, 96 per XCD
    bid = (bid & 7) * 96 + (bid >> 3);
    const int m0 = (int)(bid / 12) * 256, n0 = (int)(bid % 12) * 256;

    G8_PRE(A, Bt)

    const f32x4 fz = {0.f, 0.f, 0.f, 0.f};
    f32x4 acc[8][4];
#pragma unroll
    for (int i = 0; i < 8; ++i)
#pragma unroll
        for (int j = 0; j < 4; ++j) acc[i][j] = fz;

    G8_LOOP

#pragma unroll
    for (int mf = 0; mf < 8; ++mf) {
        const int mbase = m0 + wm * 128 + mf * 16 + g * 4;
        const int b = mbase >> 12;
        const int t = mbase & 4095;
#pragma unroll
        for (int nf = 0; nf < 4; ++nf) {
            const int n = n0 + wn * 64 + nf * 16 + cl;
            const float bv = bias[n];
            const int seg = n >> 10;
            const int hd = n & 1023;
            f32x4 v = acc[mf][nf];
            if (seg == 0) {
#pragma unroll
                for (int r = 0; r < 4; ++r)
                    Qo[(size_t)(mbase + r) * 1024 + hd] = f2bf(v[r] + bv);
            } else {
                u16* dst = (seg == 1) ? Kt : Vt;
                ushort4 pk;
                pk.x = f2bf(v[0] + bv); pk.y = f2bf(v[1] + bv);
                pk.z = f2bf(v[2] + bv); pk.w = f2bf(v[3] + bv);
                *(ushort4*)(dst + (size_t)(b * 1024 + hd) * 4096 + t) = pk;
            }
        }
    }
}

// ---------------- final projection: AO[16384x1024] @ Ot^T + o_bias -> fp32 ----------------
__global__ __launch_bounds__(512, 2) void k_gemm_out(
    const u16* __restrict__ A, const u16* __restrict__ Bt,
    const float* __restrict__ bias, float* __restrict__ out) {
    __shared__ __align__(16) char sm[131072];
    u32 bid = blockIdx.x;                      // 256 blocks, 32 per XCD
    bid = (bid & 7) * 32 + (bid >> 3);
    const int m0 = (int)(bid / 4) * 256, n0 = (int)(bid % 4) * 256;

    G8_PRE(A, Bt)

    const f32x4 fz = {0.f, 0.f, 0.f, 0.f};
    f32x4 acc[8][4];
#pragma unroll
    for (int i = 0; i < 8; ++i)
#pragma unroll
        for (int j = 0; j < 4; ++j) acc[i][j] = fz;

    G8_LOOP

#pragma unroll
    for (int mf = 0; mf < 8; ++mf) {
        const int mbase = m0 + wm * 128 + mf * 16 + g * 4;
#pragma unroll
        for (int nf = 0; nf < 4; ++nf) {
            const int n = n0 + wn * 64 + nf * 16 + cl;
            const float bv = bias[n];
            f32x4 v = acc[mf][nf];
#pragma unroll
            for (int r = 0; r < 4; ++r)
                out[(size_t)(mbase + r) * 1024 + n] = v[r] + bv;
        }
    }
}

// ---- Kp/Vp direct GEMM, no split-K. Per block: 128 primary rows (Et/Ft k_lr)
//      x 64 secondary rows (Kt/Vt d) x K=4096, BK=64, dbuf LDS 48KB.
// s=0: A=primary -> out [k_lr][d] = Kp.  s=1: A=secondary -> out [d][k_lr] = Vpt.
__global__ __launch_bounds__(512) void k_gemm_kpvp(
    const u16* __restrict__ Et, const u16* __restrict__ Ft,
    const u16* __restrict__ Kt, const u16* __restrict__ Vt,
    u16* __restrict__ Kp, u16* __restrict__ Vpt) {
    __shared__ __align__(16) char sm[49152];   // 2 x (P 16KB | S 8KB)
    const int tid = threadIdx.x, lane = tid & 63, wid = tid >> 6;
    const int cl = lane & 15, g = lane >> 4;
    const int xT = blockIdx.x;                 // 0..1  k_lr half
    const int b  = blockIdx.y;                 // 0..3
    const int hs = blockIdx.z;                 // 0..31
    const int h = hs & 15, s = hs >> 4;
    const int bh = b * 16 + h;

    // staging: primary rows rp, rp+64 (2 gld), secondary row rp (1 gld)
    const int rp = tid >> 3, c16 = tid & 7;
    const u16* P = (s ? Ft : Et) + (size_t)h * (256 * 4096);
    const u16* S = (s ? Vt : Kt) + (size_t)bh * (64 * 4096);
    const char* gP0 = (const char*)(P + (size_t)(xT * 128 + rp) * 4096)
                      + ((c16 ^ (rp & 7)) * 16);
    const char* gP1 = (const char*)(P + (size_t)(xT * 128 + rp + 64) * 4096)
                      + ((c16 ^ ((rp + 64) & 7)) * 16);
    const char* gS0 = (const char*)(S + (size_t)rp * 4096)
                      + ((c16 ^ (rp & 7)) * 16);
    const u32 lP0 = (u32)(rp * 128 + c16 * 16);
    const u32 lP1 = (u32)((rp + 64) * 128 + c16 * 16);
    const u32 lS0 = (u32)(16384 + rp * 128 + c16 * 16);

    // wave decomposition: per-wave 32x32 output
    int wa, wb; u32 baseA, baseB;
    if (s == 0) { wa = wid >> 1; wb = wid & 1; baseA = 0;     baseB = 16384; }
    else        { wa = wid >> 2; wb = wid & 3; baseA = 16384; baseB = 0;     }

    const f32x4 fz = {0.f, 0.f, 0.f, 0.f};
    f32x4 acc[2][2];
    acc[0][0] = fz; acc[0][1] = fz; acc[1][0] = fz; acc[1][1] = fz;

    gld_lds16(sm + lP0, gP0); gld_lds16(sm + lP1, gP1); gld_lds16(sm + lS0, gS0);

    u32 roff = 0;
    for (int kt = 0; kt < 64; ++kt) {
        const u32 woff = roff ^ 24576;
        if (kt < 63) {
            gld_lds16(sm + woff + lP0, gP0 + (kt + 1) * 128);
            gld_lds16(sm + woff + lP1, gP1 + (kt + 1) * 128);
            gld_lds16(sm + woff + lS0, gS0 + (kt + 1) * 128);
            asm volatile("s_waitcnt vmcnt(3)" ::: "memory");
        } else {
            asm volatile("s_waitcnt vmcnt(0)" ::: "memory");
        }
        __builtin_amdgcn_s_barrier();
        __builtin_amdgcn_sched_barrier(0);
        const char* rb = sm + roff;
        bf16x8 aF[2][2], bFr[2][2];
#pragma unroll
        for (int mf = 0; mf < 2; ++mf) {
            const int row = wa * 32 + mf * 16 + cl;
            const u32 base = baseA + (u32)row * 128;
            const int sw = (row & 7) << 4;
            aF[mf][0] = *(const bf16x8*)(rb + base + ((g * 16) ^ sw));
            aF[mf][1] = *(const bf16x8*)(rb + base + ((64 + g * 16) ^ sw));
        }
#pragma unroll
        for (int nf = 0; nf < 2; ++nf) {
            const int row = wb * 32 + nf * 16 + cl;
            const u32 base = baseB + (u32)row * 128;
            const int sw = (row & 7) << 4;
            bFr[nf][0] = *(const bf16x8*)(rb + base + ((g * 16) ^ sw));
            bFr[nf][1] = *(const bf16x8*)(rb + base + ((64 + g * 16) ^ sw));
        }
        asm volatile("s_waitcnt lgkmcnt(0)" ::: "memory");
        __builtin_amdgcn_sched_barrier(0);
        __builtin_amdgcn_s_setprio(1);
#pragma unroll
        for (int mf = 0; mf < 2; ++mf)
#pragma unroll
            for (int nf = 0; nf < 2; ++nf) {
                acc[mf][nf] = mfma16(aF[mf][0], bFr[nf][0], acc[mf][nf]);
                acc[mf][nf] = mfma16(aF[mf][1], bFr[nf][1], acc[mf][nf]);
            }
        __builtin_amdgcn_s_setprio(0);
        __builtin_amdgcn_s_barrier();
        roff = woff;
    }

    if (s == 0) {       // out rows = k_lr, cols = d
        u16* O = Kp + (size_t)bh * 16384;
#pragma unroll
        for (int mf = 0; mf < 2; ++mf) {
            const int kl = xT * 128 + wa * 32 + mf * 16 + g * 4;
#pragma unroll
            for (int nf = 0; nf < 2; ++nf) {
                const int d = wb * 32 + nf * 16 + cl;
                f32x4 v = acc[mf][nf];
#pragma unroll
                for (int r = 0; r < 4; ++r)
                    O[(size_t)(kl + r) * 64 + d] = f2bf(v[r]);
            }
        }
    } else {            // out rows = d, cols = k_lr
        u16* O = Vpt + (size_t)bh * 16384;
#pragma unroll
        for (int mf = 0; mf < 2; ++mf) {
            const int d = wa * 32 + mf * 16 + g * 4;
#pragma unroll
            for (int nf = 0; nf < 2; ++nf) {
                const int kl = xT * 128 + wb * 32 + nf * 16 + cl;
                f32x4 v = acc[mf][nf];
#pragma unroll
                for (int r = 0; r < 4; ++r)
                    O[(size_t)(d + r) * 256 + kl] = f2bf(v[r]);
            }
        }
    }
}

// ---------------- fused attention: S^T = Kp@Q^T, softmax, O^T = Vp^T@P ----------------
__global__ __launch_bounds__(256, 1) void k_attn(
    const u16* __restrict__ Q, const u16* __restrict__ Kp,
    const u16* __restrict__ Vpt, u16* __restrict__ AO) {
    __shared__ __align__(16) char sm[65536];
    const int lane = threadIdx.x & 63, wid = threadIdx.x >> 6;
    const int cl = lane & 15, g = lane >> 4;
    const int tT = blockIdx.x, h = blockIdx.y, b = blockIdx.z;
    const int bh = b * 16 + h;
    const int trow0 = b * 4096 + tT * 128 + wid * 32;
    const u16* Qb = Q + (size_t)trow0 * 1024 + h * 64;
    const u16* KpB = Kp + (size_t)bh * (256 * 64);
    const u16* VpB = Vpt + (size_t)bh * (64 * 256);
    char* sP = sm + wid * 16384;

    bf16x8 qF[2][2];
#pragma unroll
    for (int nf = 0; nf < 2; ++nf)
#pragma unroll
        for (int ks = 0; ks < 2; ++ks)
            qF[nf][ks] = *(const bf16x8*)(Qb + (size_t)(nf * 16 + cl) * 1024 + ks * 32 + g * 8);

    const f32x4 fz = {0.f, 0.f, 0.f, 0.f};
    f32x4 Sp[16][2];
#pragma unroll
    for (int mf = 0; mf < 16; ++mf) { Sp[mf][0] = fz; Sp[mf][1] = fz; }

#pragma unroll
    for (int mf = 0; mf < 16; ++mf) {
#pragma unroll
        for (int ks = 0; ks < 2; ++ks) {
            bf16x8 aF = *(const bf16x8*)(KpB + (size_t)(mf * 16 + cl) * 64 + ks * 32 + g * 8);
            Sp[mf][0] = mfma16(aF, qF[0][ks], Sp[mf][0]);
            Sp[mf][1] = mfma16(aF, qF[1][ks], Sp[mf][1]);
        }
    }

    float inv_sum[2];
#pragma unroll
    for (int nf = 0; nf < 2; ++nf) {
        float mx = -1e30f;
#pragma unroll
        for (int mf = 0; mf < 16; ++mf)
#pragma unroll
            for (int r = 0; r < 4; ++r) {
                float x = Sp[mf][nf][r] * 0.125f;
                Sp[mf][nf][r] = x;
                mx = fmaxf(mx, x);
            }
        mx = fmaxf(mx, __shfl_xor(mx, 16));
        mx = fmaxf(mx, __shfl_xor(mx, 32));
        float sum = 0.f;
#pragma unroll
        for (int mf = 0; mf < 16; ++mf)
#pragma unroll
            for (int r = 0; r < 4; ++r) {
                float p = __expf(Sp[mf][nf][r] - mx);
                Sp[mf][nf][r] = p;
                sum += p;
            }
        sum += __shfl_xor(sum, 16);
        sum += __shfl_xor(sum, 32);
        inv_sum[nf] = 1.0f / sum;

        const int tl = nf * 16 + cl;
        const int sw = (tl & 7) << 4;
#pragma unroll
        for (int mf = 0; mf < 16; ++mf) {
            uint2 pk;
            pk.x = (u32)f2bf(Sp[mf][nf][0]) | ((u32)f2bf(Sp[mf][nf][1]) << 16);
            pk.y = (u32)f2bf(Sp[mf][nf][2]) | ((u32)f2bf(Sp[mf][nf][3]) << 16);
            *(uint2*)(sP + ((tl * 512 + (mf * 16 + g * 4) * 2) ^ sw)) = pk;
        }
    }

    f32x4 Oa[4][2];
#pragma unroll
    for (int mf = 0; mf < 4; ++mf) { Oa[mf][0] = fz; Oa[mf][1] = fz; }
#pragma unroll
    for (int ks = 0; ks < 8; ++ks) {
        bf16x8 aF[4];
#pragma unroll
        for (int mf = 0; mf < 4; ++mf)
            aF[mf] = *(const bf16x8*)(VpB + (size_t)(mf * 16 + cl) * 256 + ks * 32 + g * 8);
#pragma unroll
        for (int nf = 0; nf < 2; ++nf) {
            const int tl = nf * 16 + cl;
            const int sw = (tl & 7) << 4;
            bf16x8 bF = *(const bf16x8*)(sP + ((tl * 512 + (ks * 32 + g * 8) * 2) ^ sw));
#pragma unroll
            for (int mf = 0; mf < 4; ++mf)
                Oa[mf][nf] = mfma16(aF[mf], bF, Oa[mf][nf]);
        }
    }

#pragma unroll
    for (int nf = 0; nf < 2; ++nf) {
        const int t = trow0 + nf * 16 + cl;
#pragma unroll
        for (int mf = 0; mf < 4; ++mf) {
            f32x4 v = Oa[mf][nf];
            ushort4 pk;
            pk.x = f2bf(v[0] * inv_sum[nf]); pk.y = f2bf(v[1] * inv_sum[nf]);
            pk.z = f2bf(v[2] * inv_sum[nf]); pk.w = f2bf(v[3] * inv_sum[nf]);
            *(ushort4*)(AO + (size_t)t * 1024 + h * 64 + mf * 16 + g * 4) = pk;
        }
    }
}

extern "C" void kernel_launch(void* const* d_in, const int* in_sizes, int n_in,
                              void* d_out, int out_size, void* d_ws, size_t ws_size,
                              hipStream_t stream) {
    const float* X  = (const float*)d_in[0];
    const float* Wk = (const float*)d_in[1];
    const float* Wb = (const float*)d_in[2];
    const float* E  = (const float*)d_in[3];
    const float* F  = (const float*)d_in[4];
    const float* Ok = (const float*)d_in[5];
    const float* Ob = (const float*)d_in[6];
    float* out = (float*)d_out;
    char* ws = (char*)d_ws;

    u16* Xn  = (u16*)(ws + 0);            // 32MB; reused as attn_out
    u16* Wt  = (u16*)(ws + 33554432);     // 6MB   [3072][1024]
    u16* Ot  = (u16*)(ws + 39845888);     // 2MB   [1024][1024]
    u16* Et  = (u16*)(ws + 41943040);     // 32MB  [16][256][4096]
    u16* Ft  = (u16*)(ws + 75497472);     // 32MB
    u16* Qb  = (u16*)(ws + 109051904);    // 32MB  [16384][1024]
    u16* Kt  = (u16*)(ws + 142606336);    // 32MB  [4][16][64][4096]
    u16* Vt  = (u16*)(ws + 176160768);    // 32MB
    u16* Kp  = (u16*)(ws + 209715200);    // 2MB   [64][256][64]
    u16* Vpt = (u16*)(ws + 211812352);    // 2MB   [64][64][256]
    u16* AO  = Xn;                        // Xn dead after qkv

    k_norm<<<16384, 256, 0, stream>>>(X, Xn);
    k_transpose_cast64<<<dim3(48, 16, 1), 256, 0, stream>>>(Wk, Wt, 1024, 3072, 0, 0);
    k_transpose_cast64<<<dim3(16, 16, 1), 256, 0, stream>>>(Ok, Ot, 1024, 1024, 0, 0);
    k_transpose_cast64<<<dim3(4, 64, 16), 256, 0, stream>>>(E, Et, 4096, 4096, 256, 1048576);
    k_transpose_cast64<<<dim3(4, 64, 16), 256, 0, stream>>>(F, Ft, 4096, 4096, 256, 1048576);
    k_gemm_qkv<<<768, 512, 0, stream>>>(Xn, Wt, Wb, Qb, Kt, Vt);
    k_gemm_kpvp<<<dim3(2, 4, 32), 512, 0, stream>>>(Et, Ft, Kt, Vt, Kp, Vpt);
    k_attn<<<dim3(32, 16, 4), 256, 0, stream>>>(Qb, Kp, Vpt, AO);
    k_gemm_out<<<256, 512, 0, stream>>>(AO, Ot, Ob, out);
}

// Round 9
// 360.669 us; speedup vs baseline: 1.0373x; 1.0373x over previous
//
#include <hip/hip_runtime.h>
#include <stdint.h>

typedef unsigned short u16;
typedef uint32_t u32;
typedef __bf16 bf16x8 __attribute__((ext_vector_type(8)));
typedef float f32x4 __attribute__((ext_vector_type(4)));

__device__ __forceinline__ u16 f2bf(float f) {
    u32 u = __builtin_bit_cast(u32, f);
    u += 0x7fffu + ((u >> 16) & 1u);   // RTNE
    return (u16)(u >> 16);
}

__device__ __forceinline__ f32x4 mfma16(bf16x8 a, bf16x8 b, f32x4 c) {
    return __builtin_amdgcn_mfma_f32_16x16x32_bf16(a, b, c, 0, 0, 0);
}

__device__ __forceinline__ void gld_lds16(void* lds, const void* g) {
    __builtin_amdgcn_global_load_lds(
        (__attribute__((address_space(1))) void*)(uintptr_t)g,
        (__attribute__((address_space(3))) void*)(u32)(uintptr_t)lds,
        16, 0, 0);
}

// ---------------- fused prep: norm+cast, and 4 transpose-casts ----------------
// blocks: [0,16384) norm | [16384,17152) Wk | [17152,17408) Ok
//         [17408,21504) E | [21504,25600) F
__global__ __launch_bounds__(256) void k_prep(
    const float* __restrict__ X, u16* __restrict__ Xn,
    const float* __restrict__ Wk, u16* __restrict__ Wt,
    const float* __restrict__ Ok, u16* __restrict__ Ot,
    const float* __restrict__ E, u16* __restrict__ Et,
    const float* __restrict__ F, u16* __restrict__ Ft) {
    __shared__ float tile[64][65];
    const int tid = threadIdx.x;
    int bid = blockIdx.x;

    if (bid < 16384) {                       // ---- L2-normalize row of X ----
        const int row = bid;
        const float4 v = ((const float4*)(X + (size_t)row * 1024))[tid];
        float ss = v.x * v.x + v.y * v.y + v.z * v.z + v.w * v.w;
#pragma unroll
        for (int m = 1; m < 64; m <<= 1) ss += __shfl_xor(ss, m);
        if ((tid & 63) == 0) tile[0][tid >> 6] = ss;
        __syncthreads();
        const float sc = 1.0f / sqrtf(tile[0][0] + tile[0][1] + tile[0][2] + tile[0][3]);
        ushort4 o;
        o.x = f2bf(v.x * sc); o.y = f2bf(v.y * sc);
        o.z = f2bf(v.z * sc); o.w = f2bf(v.w * sc);
        ((ushort4*)(Xn + (size_t)row * 1024))[tid] = o;
        return;
    }
    bid -= 16384;
    const float* src; u16* dst; int R, rstride, c0, r0;
    if (bid < 768) {                         // Wk: [1024][3072] -> Wt [3072][1024]
        src = Wk; dst = Wt; R = 1024; rstride = 3072;
        c0 = (bid % 48) * 64; r0 = (bid / 48) * 64;
    } else if (bid < 1024) {                 // Ok -> Ot
        const int t = bid - 768;
        src = Ok; dst = Ot; R = 1024; rstride = 1024;
        c0 = (t & 15) * 64; r0 = (t >> 4) * 64;
    } else if (bid < 5120) {                 // E [4096][16][256] -> Et [16][256][4096]
        const int t = bid - 1024;
        const int x = t & 3, y = (t >> 2) & 63, z = t >> 8;
        src = E + (size_t)z * 256; dst = Et + (size_t)z * 1048576;
        R = 4096; rstride = 4096;
        c0 = x * 64; r0 = y * 64;
    } else {                                 // F -> Ft
        const int t = bid - 5120;
        const int x = t & 3, y = (t >> 2) & 63, z = t >> 8;
        src = F + (size_t)z * 256; dst = Ft + (size_t)z * 1048576;
        R = 4096; rstride = 4096;
        c0 = x * 64; r0 = y * 64;
    }
    const int lr = tid >> 4, lc = tid & 15;
#pragma unroll
    for (int i = 0; i < 4; ++i) {
        const int r = lr + 16 * i;
        const float4 v = *(const float4*)(src + (size_t)(r0 + r) * rstride + c0 + lc * 4);
        tile[r][lc * 4 + 0] = v.x; tile[r][lc * 4 + 1] = v.y;
        tile[r][lc * 4 + 2] = v.z; tile[r][lc * 4 + 3] = v.w;
    }
    __syncthreads();
    const int c = tid >> 2, seg = tid & 3;
    u32 w[8];
#pragma unroll
    for (int j = 0; j < 8; ++j) {
        const u32 lo = f2bf(tile[seg * 16 + 2 * j][c]);
        const u32 hi = f2bf(tile[seg * 16 + 2 * j + 1][c]);
        w[j] = lo | (hi << 16);
    }
    u16* dp = dst + (size_t)(c0 + c) * R + r0 + seg * 16;
    uint4 q0; q0.x = w[0]; q0.y = w[1]; q0.z = w[2]; q0.w = w[3];
    uint4 q1; q1.x = w[4]; q1.y = w[5]; q1.z = w[6]; q1.w = w[7];
    *(uint4*)dp = q0;
    *((uint4*)dp + 1) = q1;
}

// ============ 256x256 8-phase GEMM core, pipelined ds_reads ============
#define G8_PRE(Aptr, Bptr)                                                       \
    const int tid = threadIdx.x, lane = tid & 63;                                \
    const int wid = tid >> 6, wm = wid >> 2, wn = wid & 3;                       \
    const int cl = lane & 15, g = lane >> 4;                                     \
    const int colb = (tid & 7) * 16;                                             \
    const int scb = colb ^ (((tid >> 3) & 7) << 4);                              \
    const int rbA = ((tid >> 3) & 31) + ((tid >> 8) << 7);                       \
    const int rbB = tid >> 3;                                                    \
    const char* gA = (const char*)(Aptr) + (size_t)(m0 + rbA) * 2048 + scb;      \
    const char* gB = (const char*)(Bptr) + (size_t)(n0 + rbB) * 2048 + scb;      \
    const u32 lA = (u32)(rbA * 128 + colb);                                      \
    const u32 lB = (u32)(65536 + rbB * 128 + colb);                              \
    const int xr0 = (g * 16) ^ ((cl & 7) << 4);                                  \
    const int xr1 = (64 + g * 16) ^ ((cl & 7) << 4);

#define G8_STA(q, tau, beta) gld_lds16(sm + (beta) + lA + (q) * 4096,            \
                                       gA + (q) * 65536 + (size_t)(tau) * 128);
#define G8_STB(c, tau, beta) gld_lds16(sm + (beta) + lB + (c) * 8192,            \
                                       gB + (c) * 131072 + (size_t)(tau) * 128);

#define G8_RDB(beta)                                                             \
    _Pragma("unroll") for (int nf = 0; nf < 4; ++nf) {                           \
        const u32 rb_ = (beta) + 65536 + (u32)(wn * 64 + nf * 16 + cl) * 128;    \
        bF[nf][0] = *(const bf16x8*)(sm + rb_ + xr0);                            \
        bF[nf][1] = *(const bf16x8*)(sm + rb_ + xr1);                            \
    }
#define G8_RDA2(dst, q, beta)                                                    \
    _Pragma("unroll") for (int m = 0; m < 2; ++m) {                              \
        const u32 ra_ = (beta) + (u32)(wm * 128 + (q) * 32 + m * 16 + cl) * 128; \
        dst[m][0] = *(const bf16x8*)(sm + ra_ + xr0);                            \
        dst[m][1] = *(const bf16x8*)(sm + ra_ + xr1);                            \
    }

#define G8_WAIT4 asm volatile("s_waitcnt lgkmcnt(4)" ::: "memory");              \
    __builtin_amdgcn_sched_barrier(0);
#define G8_WAIT0 asm volatile("s_waitcnt lgkmcnt(0)" ::: "memory");              \
    __builtin_amdgcn_sched_barrier(0);

#define G8_MMA(q, SRC)                                                           \
    __builtin_amdgcn_s_setprio(1);                                               \
    _Pragma("unroll") for (int m = 0; m < 2; ++m)                                \
        _Pragma("unroll") for (int nf = 0; nf < 4; ++nf) {                       \
            acc[(q)*2 + m][nf] = mfma16(SRC[m][0], bF[nf][0], acc[(q)*2 + m][nf]);\
            acc[(q)*2 + m][nf] = mfma16(SRC[m][1], bF[nf][1], acc[(q)*2 + m][nf]);\
        }                                                                        \
    __builtin_amdgcn_s_setprio(0);                                               \
    __builtin_amdgcn_s_barrier();                                                \
    __builtin_amdgcn_sched_barrier(0);

#define G8_LOOP                                                                  \
    bf16x8 aFe[2][2], aFo[2][2], bF[4][2];                                       \
    G8_STA(0, 0, 0) G8_STB(0, 0, 0) G8_STA(1, 0, 0) G8_STB(1, 0, 0)              \
    G8_STA(2, 0, 0) G8_STB(2, 0, 0) G8_STA(3, 0, 0) G8_STB(3, 0, 0)              \
    G8_STA(0, 1, 32768) G8_STB(0, 1, 32768)                                      \
    G8_STA(1, 1, 32768) G8_STB(1, 1, 32768)                                      \
    G8_STA(2, 1, 32768) G8_STB(2, 1, 32768)                                      \
    for (int it = 0; it < 8; ++it) {                                             \
        const int t1 = 2 * it + 1, t2v = 2 * it + 2, t3v = 2 * it + 3;           \
        const bool nt = (it < 7);                                                \
        /* p1 */                                                                 \
        G8_STA(3, t1, 32768) G8_STB(3, t1, 32768)                                \
        asm volatile("s_waitcnt vmcnt(8)" ::: "memory");                         \
        __builtin_amdgcn_s_barrier();                                            \
        G8_RDB(0) G8_RDA2(aFe, 0, 0) G8_RDA2(aFo, 1, 0)                          \
        G8_WAIT4 G8_MMA(0, aFe)                                                  \
        /* p2 */                                                                 \
        if (nt) { G8_STA(0, t2v, 0) G8_STB(0, t2v, 0) }                          \
        G8_RDA2(aFe, 2, 0)                                                       \
        G8_WAIT4 G8_MMA(1, aFo)                                                  \
        /* p3 */                                                                 \
        if (nt) { G8_STA(1, t2v, 0) G8_STB(1, t2v, 0) }                          \
        G8_RDA2(aFo, 3, 0)                                                       \
        G8_WAIT4 G8_MMA(2, aFe)                                                  \
        /* p4 */                                                                 \
        if (nt) { G8_STA(2, t2v, 0) G8_STB(2, t2v, 0) }                          \
        G8_WAIT0 G8_MMA(3, aFo)                                                  \
        /* p5 */                                                                 \
        if (nt) {                                                                \
            G8_STA(3, t2v, 0) G8_STB(3, t2v, 0)                                  \
            asm volatile("s_waitcnt vmcnt(8)" ::: "memory");                     \
        } else {                                                                 \
            asm volatile("s_waitcnt vmcnt(0)" ::: "memory");                     \
        }                                                                        \
        __builtin_amdgcn_s_barrier();                                            \
        G8_RDB(32768) G8_RDA2(aFe, 0, 32768) G8_RDA2(aFo, 1, 32768)              \
        G8_WAIT4 G8_MMA(0, aFe)                                                  \
        /* p6 */                                                                 \
        if (nt) { G8_STA(0, t3v, 32768) G8_STB(0, t3v, 32768) }                  \
        G8_RDA2(aFe, 2, 32768)                                                   \
        G8_WAIT4 G8_MMA(1, aFo)                                                  \
        /* p7 */                                                                 \
        if (nt) { G8_STA(1, t3v, 32768) G8_STB(1, t3v, 32768) }                  \
        G8_RDA2(aFo, 3, 32768)                                                   \
        G8_WAIT4 G8_MMA(2, aFe)                                                  \
        /* p8 */                                                                 \
        if (nt) { G8_STA(2, t3v, 32768) G8_STB(2, t3v, 32768) }                  \
        G8_WAIT0 G8_MMA(3, aFo)                                                  \
    }

// ---------------- QKV GEMM: Xn[16384x1024] @ Wt^T ----------------
// n-tile (256) lies entirely in one of Q/K/V. Q: direct stores.
// K/V: LDS-bounce epilogue -> fully-coalesced [b,h,d,t] stores.
__global__ __launch_bounds__(512, 2) void k_gemm_qkv(
    const u16* __restrict__ A, const u16* __restrict__ Bt,
    const float* __restrict__ bias,
    u16* __restrict__ Qo, u16* __restrict__ Kt, u16* __restrict__ Vt) {
    __shared__ __align__(16) char sm[131072];
    u32 bid = blockIdx.x;                      // 768 blocks, 96 per XCD
    bid = (bid & 7) * 96 + (bid >> 3);
    const int m0 = (int)(bid / 12) * 256, n0 = (int)(bid % 12) * 256;

    G8_PRE(A, Bt)

    const f32x4 fz = {0.f, 0.f, 0.f, 0.f};
    f32x4 acc[8][4];
#pragma unroll
    for (int i = 0; i < 8; ++i)
#pragma unroll
        for (int j = 0; j < 4; ++j) acc[i][j] = fz;

    G8_LOOP

    const int segb = n0 >> 10;
    if (segb == 0) {      // -------- Q: row-major direct --------
#pragma unroll
        for (int mf = 0; mf < 8; ++mf) {
            const int mbase = m0 + wm * 128 + mf * 16 + g * 4;
#pragma unroll
            for (int nf = 0; nf < 4; ++nf) {
                const int n = n0 + wn * 64 + nf * 16 + cl;
                const float bv = bias[n];
                f32x4 v = acc[mf][nf];
#pragma unroll
                for (int r = 0; r < 4; ++r)
                    Qo[(size_t)(mbase + r) * 1024 + n] = f2bf(v[r] + bv);
            }
        }
    } else {              // -------- K/V: LDS bounce, coalesced [b,h,d,t] --------
        u16* dst = (segb == 1) ? Kt : Vt;
        const int b = m0 >> 12, tbase = m0 & 4095, hd0 = n0 & 1023;
        // writer: TL[nl] = 512B row of m-values, rotated by (nl&31)*16 bytes
#pragma unroll
        for (int mf = 0; mf < 8; ++mf) {
            const int m = wm * 128 + mf * 16 + g * 4;
#pragma unroll
            for (int nf = 0; nf < 4; ++nf) {
                const int nl = wn * 64 + nf * 16 + cl;
                const float bv = bias[n0 + nl];
                f32x4 v = acc[mf][nf];
                uint2 pk;
                pk.x = (u32)f2bf(v[0] + bv) | ((u32)f2bf(v[1] + bv) << 16);
                pk.y = (u32)f2bf(v[2] + bv) | ((u32)f2bf(v[3] + bv) << 16);
                *(uint2*)(sm + nl * 512 + ((m * 2 + (nl & 31) * 16) & 511)) = pk;
            }
        }
        __syncthreads();
        // reader: 2 threads per nl row; each streams 256B (16x16B), de-rotated
        const int nl = tid >> 1, half = tid & 1;
        const u32 rot = (nl & 31) * 16;
        char* gdst = (char*)(dst + (size_t)(b * 1024 + hd0 + nl) * 4096 + tbase)
                     + half * 256;
#pragma unroll
        for (int c16 = 0; c16 < 16; ++c16) {
            const u32 c = (u32)(half * 256 + c16 * 16);   // byte offset within row
            uint4 q = *(const uint4*)(sm + nl * 512 + ((c + rot) & 511));
            *(uint4*)(gdst + c16 * 16) = q;
        }
    }
}

// ---------------- final projection: AO[16384x1024] @ Ot^T + o_bias -> fp32 ----------------
__global__ __launch_bounds__(512, 2) void k_gemm_out(
    const u16* __restrict__ A, const u16* __restrict__ Bt,
    const float* __restrict__ bias, float* __restrict__ out) {
    __shared__ __align__(16) char sm[131072];
    u32 bid = blockIdx.x;                      // 256 blocks, 32 per XCD
    bid = (bid & 7) * 32 + (bid >> 3);
    const int m0 = (int)(bid / 4) * 256, n0 = (int)(bid % 4) * 256;

    G8_PRE(A, Bt)

    const f32x4 fz = {0.f, 0.f, 0.f, 0.f};
    f32x4 acc[8][4];
#pragma unroll
    for (int i = 0; i < 8; ++i)
#pragma unroll
        for (int j = 0; j < 4; ++j) acc[i][j] = fz;

    G8_LOOP

#pragma unroll
    for (int mf = 0; mf < 8; ++mf) {
        const int mbase = m0 + wm * 128 + mf * 16 + g * 4;
#pragma unroll
        for (int nf = 0; nf < 4; ++nf) {
            const int n = n0 + wn * 64 + nf * 16 + cl;
            const float bv = bias[n];
            f32x4 v = acc[mf][nf];
#pragma unroll
            for (int r = 0; r < 4; ++r)
                out[(size_t)(mbase + r) * 1024 + n] = v[r] + bv;
        }
    }
}

// ---- Kp/Vp split-K GEMM. s=0: Kp-partials [k_lr][dcat].
//      s=1 (operand-swapped): Vp^T-partials [dcat][k_lr]. fp32 Pp out. ----
__global__ __launch_bounds__(512) void k_gemm_kpvp(
    const u16* __restrict__ Et, const u16* __restrict__ Ft,
    const u16* __restrict__ Kt, const u16* __restrict__ Vt,
    float* __restrict__ Pp) {
    __shared__ __align__(16) char sm[49152];   // 2 x (A 8KB | B 16KB)
    const int tid = threadIdx.x, lane = tid & 63, wid = tid >> 6;
    const int wm = wid >> 2, wn = wid & 3;
    const int cl = lane & 15, g = lane >> 4;
    const int mT = blockIdx.x;                 // 0..1   M half
    const int hs = blockIdx.y;                 // 0..31  h = hs&15, s = hs>>4
    const int h = hs & 15, s = hs >> 4;
    const int ks = blockIdx.z;                 // 0..3   K split (1024 each)

    const int rA = tid >> 2, c16 = tid & 3;
    const int scol = (c16 ^ ((rA >> 1) & 3)) * 8;      // pre-swizzled source col
    const u16 *gA, *gB0, *gB1;
    if (s == 0) {   // A = Et[h] rows (k_lr), B = Kt rows (dcat)
        gA = Et + (size_t)h * (256 * 4096) + (size_t)(mT * 128 + rA) * 4096
             + ks * 1024 + scol;
        gB0 = Kt + (size_t)((((rA >> 6) * 16 + h) * 64) + (rA & 63)) * 4096
              + ks * 1024 + scol;
        const int rB1 = rA + 128;
        gB1 = Kt + (size_t)((((rB1 >> 6) * 16 + h) * 64) + (rB1 & 63)) * 4096
              + ks * 1024 + scol;
    } else {        // A = Vt rows (dcat), B = Ft[h] rows (k_lr)
        const int dc = mT * 128 + rA;
        gA = Vt + (size_t)(((dc >> 6) * 16 + h) * 64 + (dc & 63)) * 4096
             + ks * 1024 + scol;
        gB0 = Ft + (size_t)h * (256 * 4096) + (size_t)rA * 4096 + ks * 1024 + scol;
        gB1 = gB0 + (size_t)128 * 4096;
    }
    const u32 lA = (u32)(rA * 64 + c16 * 16);
    const u32 lB0 = (u32)(8192 + rA * 64 + c16 * 16);
    const u32 lB1 = lB0 + 128 * 64;
    const int xsw = (g ^ ((cl >> 1) & 3)) * 16;        // read-side swizzle

    const f32x4 fz = {0.f, 0.f, 0.f, 0.f};
    f32x4 acc[4][4];
#pragma unroll
    for (int i = 0; i < 4; ++i)
#pragma unroll
        for (int j = 0; j < 4; ++j) acc[i][j] = fz;

    gld_lds16(sm + lA, gA); gld_lds16(sm + lB0, gB0); gld_lds16(sm + lB1, gB1);

    u32 roff = 0;
    for (int kt = 0; kt < 32; ++kt) {
        const u32 woff = roff ^ 24576;
        if (kt < 31) {
            gld_lds16(sm + woff + lA, gA + (kt + 1) * 32);
            gld_lds16(sm + woff + lB0, gB0 + (kt + 1) * 32);
            gld_lds16(sm + woff + lB1, gB1 + (kt + 1) * 32);
            asm volatile("s_waitcnt vmcnt(3)" ::: "memory");
        } else {
            asm volatile("s_waitcnt vmcnt(0)" ::: "memory");
        }
        __builtin_amdgcn_s_barrier();
        __builtin_amdgcn_sched_barrier(0);
        const char* rb = sm + roff;
        bf16x8 aF[4], bF[4];
#pragma unroll
        for (int mf = 0; mf < 4; ++mf)
            aF[mf] = *(const bf16x8*)(rb + (wm * 64 + mf * 16 + cl) * 64 + xsw);
#pragma unroll
        for (int nf = 0; nf < 4; ++nf)
            bF[nf] = *(const bf16x8*)(rb + 8192 + (wn * 64 + nf * 16 + cl) * 64 + xsw);
        asm volatile("s_waitcnt lgkmcnt(0)" ::: "memory");
        __builtin_amdgcn_sched_barrier(0);
        __builtin_amdgcn_s_setprio(1);
#pragma unroll
        for (int mf = 0; mf < 4; ++mf)
#pragma unroll
            for (int nf = 0; nf < 4; ++nf)
                acc[mf][nf] = mfma16(aF[mf], bF[nf], acc[mf][nf]);
        __builtin_amdgcn_s_setprio(0);
        asm volatile("s_waitcnt lgkmcnt(0)" ::: "memory");
        __builtin_amdgcn_s_barrier();
        roff = woff;
    }

    float* P = Pp + ((size_t)(ks * 32 + hs) << 16);
#pragma unroll
    for (int mf = 0; mf < 4; ++mf) {
        const int m = mT * 128 + wm * 64 + mf * 16 + g * 4;
#pragma unroll
        for (int nf = 0; nf < 4; ++nf) {
            const int nn = wn * 64 + nf * 16 + cl;
            f32x4 v = acc[mf][nf];
#pragma unroll
            for (int r = 0; r < 4; ++r)
                P[(size_t)(m + r) * 256 + nn] = v[r];
        }
    }
}

// ---- reduce 4 K-splits, cast. sf=0: Kp [bh][k][d]; sf=1: Vpt [bh][d][k] ----
__global__ __launch_bounds__(256) void k_red(const float* __restrict__ Pp,
                                             u16* __restrict__ Kp,
                                             u16* __restrict__ Vpt) {
    const int e = blockIdx.x * 256 + threadIdx.x;
    const int hs = e >> 14;
    const int rem = (e & 16383) * 4;
    float4 sum = {0.f, 0.f, 0.f, 0.f};
#pragma unroll
    for (int ks = 0; ks < 4; ++ks) {
        const float4 v = *(const float4*)(Pp + (((size_t)(ks * 32 + hs)) << 16) + rem);
        sum.x += v.x; sum.y += v.y; sum.z += v.z; sum.w += v.w;
    }
    const int m = rem >> 8, col = rem & 255;
    const int h = hs & 15, sf = hs >> 4;
    ushort4 pk;
    pk.x = f2bf(sum.x); pk.y = f2bf(sum.y);
    pk.z = f2bf(sum.z); pk.w = f2bf(sum.w);
    if (sf == 0) {
        const int bh = (col >> 6) * 16 + h, d0 = col & 63;
        *(ushort4*)(Kp + (size_t)bh * 16384 + m * 64 + d0) = pk;
    } else {
        const int bh = (m >> 6) * 16 + h, d = m & 63;
        *(ushort4*)(Vpt + (size_t)bh * 16384 + d * 256 + col) = pk;
    }
}

// ---------------- fused attention: S^T = Kp@Q^T, softmax, O^T = Vp^T@P ----------------
__global__ __launch_bounds__(256, 1) void k_attn(
    const u16* __restrict__ Q, const u16* __restrict__ Kp,
    const u16* __restrict__ Vpt, u16* __restrict__ AO) {
    __shared__ __align__(16) char sm[65536];
    const int lane = threadIdx.x & 63, wid = threadIdx.x >> 6;
    const int cl = lane & 15, g = lane >> 4;
    const int tT = blockIdx.x, h = blockIdx.y, b = blockIdx.z;
    const int bh = b * 16 + h;
    const int trow0 = b * 4096 + tT * 128 + wid * 32;
    const u16* Qb = Q + (size_t)trow0 * 1024 + h * 64;
    const u16* KpB = Kp + (size_t)bh * (256 * 64);
    const u16* VpB = Vpt + (size_t)bh * (64 * 256);
    char* sP = sm + wid * 16384;

    bf16x8 qF[2][2];
#pragma unroll
    for (int nf = 0; nf < 2; ++nf)
#pragma unroll
        for (int ks = 0; ks < 2; ++ks)
            qF[nf][ks] = *(const bf16x8*)(Qb + (size_t)(nf * 16 + cl) * 1024 + ks * 32 + g * 8);

    const f32x4 fz = {0.f, 0.f, 0.f, 0.f};
    f32x4 Sp[16][2];
#pragma unroll
    for (int mf = 0; mf < 16; ++mf) { Sp[mf][0] = fz; Sp[mf][1] = fz; }

#pragma unroll
    for (int mf = 0; mf < 16; ++mf) {
#pragma unroll
        for (int ks = 0; ks < 2; ++ks) {
            bf16x8 aF = *(const bf16x8*)(KpB + (size_t)(mf * 16 + cl) * 64 + ks * 32 + g * 8);
            Sp[mf][0] = mfma16(aF, qF[0][ks], Sp[mf][0]);
            Sp[mf][1] = mfma16(aF, qF[1][ks], Sp[mf][1]);
        }
    }

    float inv_sum[2];
#pragma unroll
    for (int nf = 0; nf < 2; ++nf) {
        float mx = -1e30f;
#pragma unroll
        for (int mf = 0; mf < 16; ++mf)
#pragma unroll
            for (int r = 0; r < 4; ++r) {
                float x = Sp[mf][nf][r] * 0.125f;
                Sp[mf][nf][r] = x;
                mx = fmaxf(mx, x);
            }
        mx = fmaxf(mx, __shfl_xor(mx, 16));
        mx = fmaxf(mx, __shfl_xor(mx, 32));
        float sum = 0.f;
#pragma unroll
        for (int mf = 0; mf < 16; ++mf)
#pragma unroll
            for (int r = 0; r < 4; ++r) {
                float p = __expf(Sp[mf][nf][r] - mx);
                Sp[mf][nf][r] = p;
                sum += p;
            }
        sum += __shfl_xor(sum, 16);
        sum += __shfl_xor(sum, 32);
        inv_sum[nf] = 1.0f / sum;

        const int tl = nf * 16 + cl;
        const int sw = (tl & 7) << 4;
#pragma unroll
        for (int mf = 0; mf < 16; ++mf) {
            uint2 pk;
            pk.x = (u32)f2bf(Sp[mf][nf][0]) | ((u32)f2bf(Sp[mf][nf][1]) << 16);
            pk.y = (u32)f2bf(Sp[mf][nf][2]) | ((u32)f2bf(Sp[mf][nf][3]) << 16);
            *(uint2*)(sP + ((tl * 512 + (mf * 16 + g * 4) * 2) ^ sw)) = pk;
        }
    }

    f32x4 Oa[4][2];
#pragma unroll
    for (int mf = 0; mf < 4; ++mf) { Oa[mf][0] = fz; Oa[mf][1] = fz; }
#pragma unroll
    for (int ks = 0; ks < 8; ++ks) {
        bf16x8 aF[4];
#pragma unroll
        for (int mf = 0; mf < 4; ++mf)
            aF[mf] = *(const bf16x8*)(VpB + (size_t)(mf * 16 + cl) * 256 + ks * 32 + g * 8);
#pragma unroll
        for (int nf = 0; nf < 2; ++nf) {
            const int tl = nf * 16 + cl;
            const int sw = (tl & 7) << 4;
            bf16x8 bF = *(const bf16x8*)(sP + ((tl * 512 + (ks * 32 + g * 8) * 2) ^ sw));
#pragma unroll
            for (int mf = 0; mf < 4; ++mf)
                Oa[mf][nf] = mfma16(aF[mf], bF, Oa[mf][nf]);
        }
    }

#pragma unroll
    for (int nf = 0; nf < 2; ++nf) {
        const int t = trow0 + nf * 16 + cl;
#pragma unroll
        for (int mf = 0; mf < 4; ++mf) {
            f32x4 v = Oa[mf][nf];
            ushort4 pk;
            pk.x = f2bf(v[0] * inv_sum[nf]); pk.y = f2bf(v[1] * inv_sum[nf]);
            pk.z = f2bf(v[2] * inv_sum[nf]); pk.w = f2bf(v[3] * inv_sum[nf]);
            *(ushort4*)(AO + (size_t)t * 1024 + h * 64 + mf * 16 + g * 4) = pk;
        }
    }
}

extern "C" void kernel_launch(void* const* d_in, const int* in_sizes, int n_in,
                              void* d_out, int out_size, void* d_ws, size_t ws_size,
                              hipStream_t stream) {
    const float* X  = (const float*)d_in[0];
    const float* Wk = (const float*)d_in[1];
    const float* Wb = (const float*)d_in[2];
    const float* E  = (const float*)d_in[3];
    const float* F  = (const float*)d_in[4];
    const float* Ok = (const float*)d_in[5];
    const float* Ob = (const float*)d_in[6];
    float* out = (float*)d_out;
    char* ws = (char*)d_ws;

    u16* Xn  = (u16*)(ws + 0);            // 32MB; reused as Pp (kpvp) then AO (attn)
    u16* Wt  = (u16*)(ws + 33554432);     // 6MB   [3072][1024]
    u16* Ot  = (u16*)(ws + 39845888);     // 2MB   [1024][1024]
    u16* Et  = (u16*)(ws + 41943040);     // 32MB  [16][256][4096]
    u16* Ft  = (u16*)(ws + 75497472);     // 32MB
    u16* Qb  = (u16*)(ws + 109051904);    // 32MB  [16384][1024]
    u16* Kt  = (u16*)(ws + 142606336);    // 32MB  [4][16][64][4096]
    u16* Vt  = (u16*)(ws + 176160768);    // 32MB
    u16* Kp  = (u16*)(ws + 209715200);    // 2MB   [64][256][64]
    u16* Vpt = (u16*)(ws + 211812352);    // 2MB   [64][64][256]
    float* Pp = (float*)(ws + 0);         // 32MB fp32 partials (Xn dead after qkv)
    u16* AO  = Xn;                        // Pp dead after k_red

    k_prep<<<25600, 256, 0, stream>>>(X, Xn, Wk, Wt, Ok, Ot, E, Et, F, Ft);
    k_gemm_qkv<<<768, 512, 0, stream>>>(Xn, Wt, Wb, Qb, Kt, Vt);
    k_gemm_kpvp<<<dim3(2, 32, 4), 512, 0, stream>>>(Et, Ft, Kt, Vt, Pp);
    k_red<<<2048, 256, 0, stream>>>(Pp, Kp, Vpt);
    k_attn<<<dim3(32, 16, 4), 256, 0, stream>>>(Qb, Kp, Vpt, AO);
    k_gemm_out<<<256, 512, 0, stream>>>(AO, Ot, Ob, out);
}

// Round 10
// 338.491 us; speedup vs baseline: 1.1053x; 1.0655x over previous
//
#include <hip/hip_runtime.h>
#include <stdint.h>

typedef unsigned short u16;
typedef uint32_t u32;
typedef __bf16 bf16x8 __attribute__((ext_vector_type(8)));
typedef float f32x4 __attribute__((ext_vector_type(4)));

__device__ __forceinline__ u16 f2bf(float f) {
    u32 u = __builtin_bit_cast(u32, f);
    u += 0x7fffu + ((u >> 16) & 1u);   // RTNE
    return (u16)(u >> 16);
}

__device__ __forceinline__ f32x4 mfma16(bf16x8 a, bf16x8 b, f32x4 c) {
    return __builtin_amdgcn_mfma_f32_16x16x32_bf16(a, b, c, 0, 0, 0);
}

__device__ __forceinline__ void gld_lds16(void* lds, const void* g) {
    __builtin_amdgcn_global_load_lds(
        (__attribute__((address_space(1))) void*)(uintptr_t)g,
        (__attribute__((address_space(3))) void*)(u32)(uintptr_t)lds,
        16, 0, 0);
}

// ---------------- fused prep: norm+cast, and 4 transpose-casts ----------------
// blocks: [0,16384) norm | [16384,17152) Wk | [17152,17408) Ok
//         [17408,21504) E | [21504,25600) F
__global__ __launch_bounds__(256) void k_prep(
    const float* __restrict__ X, u16* __restrict__ Xn,
    const float* __restrict__ Wk, u16* __restrict__ Wt,
    const float* __restrict__ Ok, u16* __restrict__ Ot,
    const float* __restrict__ E, u16* __restrict__ Et,
    const float* __restrict__ F, u16* __restrict__ Ft) {
    __shared__ float tile[64][65];
    const int tid = threadIdx.x;
    int bid = blockIdx.x;

    if (bid < 16384) {                       // ---- L2-normalize row of X ----
        const int row = bid;
        const float4 v = ((const float4*)(X + (size_t)row * 1024))[tid];
        float ss = v.x * v.x + v.y * v.y + v.z * v.z + v.w * v.w;
#pragma unroll
        for (int m = 1; m < 64; m <<= 1) ss += __shfl_xor(ss, m);
        if ((tid & 63) == 0) tile[0][tid >> 6] = ss;
        __syncthreads();
        const float sc = 1.0f / sqrtf(tile[0][0] + tile[0][1] + tile[0][2] + tile[0][3]);
        ushort4 o;
        o.x = f2bf(v.x * sc); o.y = f2bf(v.y * sc);
        o.z = f2bf(v.z * sc); o.w = f2bf(v.w * sc);
        ((ushort4*)(Xn + (size_t)row * 1024))[tid] = o;
        return;
    }
    bid -= 16384;
    const float* src; u16* dst; int R, rstride, c0, r0;
    if (bid < 768) {                         // Wk: [1024][3072] -> Wt [3072][1024]
        src = Wk; dst = Wt; R = 1024; rstride = 3072;
        c0 = (bid % 48) * 64; r0 = (bid / 48) * 64;
    } else if (bid < 1024) {                 // Ok -> Ot
        const int t = bid - 768;
        src = Ok; dst = Ot; R = 1024; rstride = 1024;
        c0 = (t & 15) * 64; r0 = (t >> 4) * 64;
    } else if (bid < 5120) {                 // E [4096][16][256] -> Et [16][256][4096]
        const int t = bid - 1024;
        const int x = t & 3, y = (t >> 2) & 63, z = t >> 8;
        src = E + (size_t)z * 256; dst = Et + (size_t)z * 1048576;
        R = 4096; rstride = 4096;
        c0 = x * 64; r0 = y * 64;
    } else {                                 // F -> Ft
        const int t = bid - 5120;
        const int x = t & 3, y = (t >> 2) & 63, z = t >> 8;
        src = F + (size_t)z * 256; dst = Ft + (size_t)z * 1048576;
        R = 4096; rstride = 4096;
        c0 = x * 64; r0 = y * 64;
    }
    const int lr = tid >> 4, lc = tid & 15;
#pragma unroll
    for (int i = 0; i < 4; ++i) {
        const int r = lr + 16 * i;
        const float4 v = *(const float4*)(src + (size_t)(r0 + r) * rstride + c0 + lc * 4);
        tile[r][lc * 4 + 0] = v.x; tile[r][lc * 4 + 1] = v.y;
        tile[r][lc * 4 + 2] = v.z; tile[r][lc * 4 + 3] = v.w;
    }
    __syncthreads();
    const int c = tid >> 2, seg = tid & 3;
    u32 w[8];
#pragma unroll
    for (int j = 0; j < 8; ++j) {
        const u32 lo = f2bf(tile[seg * 16 + 2 * j][c]);
        const u32 hi = f2bf(tile[seg * 16 + 2 * j + 1][c]);
        w[j] = lo | (hi << 16);
    }
    u16* dp = dst + (size_t)(c0 + c) * R + r0 + seg * 16;
    uint4 q0; q0.x = w[0]; q0.y = w[1]; q0.z = w[2]; q0.w = w[3];
    uint4 q1; q1.x = w[4]; q1.y = w[5]; q1.z = w[6]; q1.w = w[7];
    *(uint4*)dp = q0;
    *((uint4*)dp + 1) = q1;
}

// ============ 256x256 8-phase GEMM core, pipelined ds_reads ============
#define G8_PRE(Aptr, Bptr)                                                       \
    const int tid = threadIdx.x, lane = tid & 63;                                \
    const int wid = tid >> 6, wm = wid >> 2, wn = wid & 3;                       \
    const int cl = lane & 15, g = lane >> 4;                                     \
    const int colb = (tid & 7) * 16;                                             \
    const int scb = colb ^ (((tid >> 3) & 7) << 4);                              \
    const int rbA = ((tid >> 3) & 31) + ((tid >> 8) << 7);                       \
    const int rbB = tid >> 3;                                                    \
    const char* gA = (const char*)(Aptr) + (size_t)(m0 + rbA) * 2048 + scb;      \
    const char* gB = (const char*)(Bptr) + (size_t)(n0 + rbB) * 2048 + scb;      \
    const u32 lA = (u32)(rbA * 128 + colb);                                      \
    const u32 lB = (u32)(65536 + rbB * 128 + colb);                              \
    const int xr0 = (g * 16) ^ ((cl & 7) << 4);                                  \
    const int xr1 = (64 + g * 16) ^ ((cl & 7) << 4);

#define G8_STA(q, tau, beta) gld_lds16(sm + (beta) + lA + (q) * 4096,            \
                                       gA + (q) * 65536 + (size_t)(tau) * 128);
#define G8_STB(c, tau, beta) gld_lds16(sm + (beta) + lB + (c) * 8192,            \
                                       gB + (c) * 131072 + (size_t)(tau) * 128);

#define G8_RDB(beta)                                                             \
    _Pragma("unroll") for (int nf = 0; nf < 4; ++nf) {                           \
        const u32 rb_ = (beta) + 65536 + (u32)(wn * 64 + nf * 16 + cl) * 128;    \
        bF[nf][0] = *(const bf16x8*)(sm + rb_ + xr0);                            \
        bF[nf][1] = *(const bf16x8*)(sm + rb_ + xr1);                            \
    }
#define G8_RDA2(dst, q, beta)                                                    \
    _Pragma("unroll") for (int m = 0; m < 2; ++m) {                              \
        const u32 ra_ = (beta) + (u32)(wm * 128 + (q) * 32 + m * 16 + cl) * 128; \
        dst[m][0] = *(const bf16x8*)(sm + ra_ + xr0);                            \
        dst[m][1] = *(const bf16x8*)(sm + ra_ + xr1);                            \
    }

#define G8_WAIT4 asm volatile("s_waitcnt lgkmcnt(4)" ::: "memory");              \
    __builtin_amdgcn_sched_barrier(0);
#define G8_WAIT0 asm volatile("s_waitcnt lgkmcnt(0)" ::: "memory");              \
    __builtin_amdgcn_sched_barrier(0);

#define G8_MMA(q, SRC)                                                           \
    __builtin_amdgcn_s_setprio(1);                                               \
    _Pragma("unroll") for (int m = 0; m < 2; ++m)                                \
        _Pragma("unroll") for (int nf = 0; nf < 4; ++nf) {                       \
            acc[(q)*2 + m][nf] = mfma16(SRC[m][0], bF[nf][0], acc[(q)*2 + m][nf]);\
            acc[(q)*2 + m][nf] = mfma16(SRC[m][1], bF[nf][1], acc[(q)*2 + m][nf]);\
        }                                                                        \
    __builtin_amdgcn_s_setprio(0);                                               \
    __builtin_amdgcn_s_barrier();                                                \
    __builtin_amdgcn_sched_barrier(0);

#define G8_LOOP                                                                  \
    bf16x8 aFe[2][2], aFo[2][2], bF[4][2];                                       \
    G8_STA(0, 0, 0) G8_STB(0, 0, 0) G8_STA(1, 0, 0) G8_STB(1, 0, 0)              \
    G8_STA(2, 0, 0) G8_STB(2, 0, 0) G8_STA(3, 0, 0) G8_STB(3, 0, 0)              \
    G8_STA(0, 1, 32768) G8_STB(0, 1, 32768)                                      \
    G8_STA(1, 1, 32768) G8_STB(1, 1, 32768)                                      \
    G8_STA(2, 1, 32768) G8_STB(2, 1, 32768)                                      \
    for (int it = 0; it < 8; ++it) {                                             \
        const int t1 = 2 * it + 1, t2v = 2 * it + 2, t3v = 2 * it + 3;           \
        const bool nt = (it < 7);                                                \
        /* p1 */                                                                 \
        G8_STA(3, t1, 32768) G8_STB(3, t1, 32768)                                \
        asm volatile("s_waitcnt vmcnt(8)" ::: "memory");                         \
        __builtin_amdgcn_s_barrier();                                            \
        G8_RDB(0) G8_RDA2(aFe, 0, 0) G8_RDA2(aFo, 1, 0)                          \
        G8_WAIT4 G8_MMA(0, aFe)                                                  \
        /* p2 */                                                                 \
        if (nt) { G8_STA(0, t2v, 0) G8_STB(0, t2v, 0) }                          \
        G8_RDA2(aFe, 2, 0)                                                       \
        G8_WAIT4 G8_MMA(1, aFo)                                                  \
        /* p3 */                                                                 \
        if (nt) { G8_STA(1, t2v, 0) G8_STB(1, t2v, 0) }                          \
        G8_RDA2(aFo, 3, 0)                                                       \
        G8_WAIT4 G8_MMA(2, aFe)                                                  \
        /* p4 */                                                                 \
        if (nt) { G8_STA(2, t2v, 0) G8_STB(2, t2v, 0) }                          \
        G8_WAIT0 G8_MMA(3, aFo)                                                  \
        /* p5 */                                                                 \
        if (nt) {                                                                \
            G8_STA(3, t2v, 0) G8_STB(3, t2v, 0)                                  \
            asm volatile("s_waitcnt vmcnt(8)" ::: "memory");                     \
        } else {                                                                 \
            asm volatile("s_waitcnt vmcnt(0)" ::: "memory");                     \
        }                                                                        \
        __builtin_amdgcn_s_barrier();                                            \
        G8_RDB(32768) G8_RDA2(aFe, 0, 32768) G8_RDA2(aFo, 1, 32768)              \
        G8_WAIT4 G8_MMA(0, aFe)                                                  \
        /* p6 */                                                                 \
        if (nt) { G8_STA(0, t3v, 32768) G8_STB(0, t3v, 32768) }                  \
        G8_RDA2(aFe, 2, 32768)                                                   \
        G8_WAIT4 G8_MMA(1, aFo)                                                  \
        /* p7 */                                                                 \
        if (nt) { G8_STA(1, t3v, 32768) G8_STB(1, t3v, 32768) }                  \
        G8_RDA2(aFo, 3, 32768)                                                   \
        G8_WAIT4 G8_MMA(2, aFe)                                                  \
        /* p8 */                                                                 \
        if (nt) { G8_STA(2, t3v, 32768) G8_STB(2, t3v, 32768) }                  \
        G8_WAIT0 G8_MMA(3, aFo)                                                  \
    }

// ---------------- QKV GEMM: Xn[16384x1024] @ Wt^T ----------------
// n-tile (256) lies entirely in one of Q/K/V. Q: row-major direct.
// K/V: direct ushort4 scatter to [b,h,d,t] (measured-best; LDS bounce regressed).
__global__ __launch_bounds__(512, 2) void k_gemm_qkv(
    const u16* __restrict__ A, const u16* __restrict__ Bt,
    const float* __restrict__ bias,
    u16* __restrict__ Qo, u16* __restrict__ Kt, u16* __restrict__ Vt) {
    __shared__ __align__(16) char sm[131072];
    u32 bid = blockIdx.x;                      // 768 blocks, 96 per XCD
    bid = (bid & 7) * 96 + (bid >> 3);
    const int m0 = (int)(bid / 12) * 256, n0 = (int)(bid % 12) * 256;

    G8_PRE(A, Bt)

    const f32x4 fz = {0.f, 0.f, 0.f, 0.f};
    f32x4 acc[8][4];
#pragma unroll
    for (int i = 0; i < 8; ++i)
#pragma unroll
        for (int j = 0; j < 4; ++j) acc[i][j] = fz;

    G8_LOOP

    const int segb = n0 >> 10;
    if (segb == 0) {      // -------- Q: row-major direct --------
#pragma unroll
        for (int mf = 0; mf < 8; ++mf) {
            const int mbase = m0 + wm * 128 + mf * 16 + g * 4;
#pragma unroll
            for (int nf = 0; nf < 4; ++nf) {
                const int n = n0 + wn * 64 + nf * 16 + cl;
                const float bv = bias[n];
                f32x4 v = acc[mf][nf];
#pragma unroll
                for (int r = 0; r < 4; ++r)
                    Qo[(size_t)(mbase + r) * 1024 + n] = f2bf(v[r] + bv);
            }
        }
    } else {              // -------- K/V: direct scatter [b,h,d,t] --------
        u16* dst = (segb == 1) ? Kt : Vt;
        const int hd0 = n0 & 1023;
#pragma unroll
        for (int mf = 0; mf < 8; ++mf) {
            const int mbase = m0 + wm * 128 + mf * 16 + g * 4;
            const int b = mbase >> 12;
            const int t = mbase & 4095;
#pragma unroll
            for (int nf = 0; nf < 4; ++nf) {
                const int nl = wn * 64 + nf * 16 + cl;
                const float bv = bias[n0 + nl];
                const int hd = hd0 + nl;
                f32x4 v = acc[mf][nf];
                ushort4 pk;
                pk.x = f2bf(v[0] + bv); pk.y = f2bf(v[1] + bv);
                pk.z = f2bf(v[2] + bv); pk.w = f2bf(v[3] + bv);
                *(ushort4*)(dst + (size_t)(b * 1024 + hd) * 4096 + t) = pk;
            }
        }
    }
}

// ---------------- final projection: AO[16384x1024] @ Ot^T + o_bias -> fp32 ----------------
__global__ __launch_bounds__(512, 2) void k_gemm_out(
    const u16* __restrict__ A, const u16* __restrict__ Bt,
    const float* __restrict__ bias, float* __restrict__ out) {
    __shared__ __align__(16) char sm[131072];
    u32 bid = blockIdx.x;                      // 256 blocks, 32 per XCD
    bid = (bid & 7) * 32 + (bid >> 3);
    const int m0 = (int)(bid / 4) * 256, n0 = (int)(bid % 4) * 256;

    G8_PRE(A, Bt)

    const f32x4 fz = {0.f, 0.f, 0.f, 0.f};
    f32x4 acc[8][4];
#pragma unroll
    for (int i = 0; i < 8; ++i)
#pragma unroll
        for (int j = 0; j < 4; ++j) acc[i][j] = fz;

    G8_LOOP

#pragma unroll
    for (int mf = 0; mf < 8; ++mf) {
        const int mbase = m0 + wm * 128 + mf * 16 + g * 4;
#pragma unroll
        for (int nf = 0; nf < 4; ++nf) {
            const int n = n0 + wn * 64 + nf * 16 + cl;
            const float bv = bias[n];
            f32x4 v = acc[mf][nf];
#pragma unroll
            for (int r = 0; r < 4; ++r)
                out[(size_t)(mbase + r) * 1024 + n] = v[r] + bv;
        }
    }
}

// ---- Kp/Vp split-K GEMM. s=0: Kp-partials [k_lr][dcat].
//      s=1 (operand-swapped): Vp^T-partials [dcat][k_lr]. fp32 Pp out. ----
__global__ __launch_bounds__(512) void k_gemm_kpvp(
    const u16* __restrict__ Et, const u16* __restrict__ Ft,
    const u16* __restrict__ Kt, const u16* __restrict__ Vt,
    float* __restrict__ Pp) {
    __shared__ __align__(16) char sm[49152];   // 2 x (A 8KB | B 16KB)
    const int tid = threadIdx.x, lane = tid & 63, wid = tid >> 6;
    const int wm = wid >> 2, wn = wid & 3;
    const int cl = lane & 15, g = lane >> 4;
    const int mT = blockIdx.x;                 // 0..1   M half
    const int hs = blockIdx.y;                 // 0..31  h = hs&15, s = hs>>4
    const int h = hs & 15, s = hs >> 4;
    const int ks = blockIdx.z;                 // 0..3   K split (1024 each)

    const int rA = tid >> 2, c16 = tid & 3;
    const int scol = (c16 ^ ((rA >> 1) & 3)) * 8;      // pre-swizzled source col
    const u16 *gA, *gB0, *gB1;
    if (s == 0) {   // A = Et[h] rows (k_lr), B = Kt rows (dcat)
        gA = Et + (size_t)h * (256 * 4096) + (size_t)(mT * 128 + rA) * 4096
             + ks * 1024 + scol;
        gB0 = Kt + (size_t)((((rA >> 6) * 16 + h) * 64) + (rA & 63)) * 4096
              + ks * 1024 + scol;
        const int rB1 = rA + 128;
        gB1 = Kt + (size_t)((((rB1 >> 6) * 16 + h) * 64) + (rB1 & 63)) * 4096
              + ks * 1024 + scol;
    } else {        // A = Vt rows (dcat), B = Ft[h] rows (k_lr)
        const int dc = mT * 128 + rA;
        gA = Vt + (size_t)(((dc >> 6) * 16 + h) * 64 + (dc & 63)) * 4096
             + ks * 1024 + scol;
        gB0 = Ft + (size_t)h * (256 * 4096) + (size_t)rA * 4096 + ks * 1024 + scol;
        gB1 = gB0 + (size_t)128 * 4096;
    }
    const u32 lA = (u32)(rA * 64 + c16 * 16);
    const u32 lB0 = (u32)(8192 + rA * 64 + c16 * 16);
    const u32 lB1 = lB0 + 128 * 64;
    const int xsw = (g ^ ((cl >> 1) & 3)) * 16;        // read-side swizzle

    const f32x4 fz = {0.f, 0.f, 0.f, 0.f};
    f32x4 acc[4][4];
#pragma unroll
    for (int i = 0; i < 4; ++i)
#pragma unroll
        for (int j = 0; j < 4; ++j) acc[i][j] = fz;

    gld_lds16(sm + lA, gA); gld_lds16(sm + lB0, gB0); gld_lds16(sm + lB1, gB1);

    u32 roff = 0;
    for (int kt = 0; kt < 32; ++kt) {
        const u32 woff = roff ^ 24576;
        if (kt < 31) {
            gld_lds16(sm + woff + lA, gA + (kt + 1) * 32);
            gld_lds16(sm + woff + lB0, gB0 + (kt + 1) * 32);
            gld_lds16(sm + woff + lB1, gB1 + (kt + 1) * 32);
            asm volatile("s_waitcnt vmcnt(3)" ::: "memory");
        } else {
            asm volatile("s_waitcnt vmcnt(0)" ::: "memory");
        }
        __builtin_amdgcn_s_barrier();
        __builtin_amdgcn_sched_barrier(0);
        const char* rb = sm + roff;
        bf16x8 aF[4], bF[4];
#pragma unroll
        for (int mf = 0; mf < 4; ++mf)
            aF[mf] = *(const bf16x8*)(rb + (wm * 64 + mf * 16 + cl) * 64 + xsw);
#pragma unroll
        for (int nf = 0; nf < 4; ++nf)
            bF[nf] = *(const bf16x8*)(rb + 8192 + (wn * 64 + nf * 16 + cl) * 64 + xsw);
        asm volatile("s_waitcnt lgkmcnt(0)" ::: "memory");
        __builtin_amdgcn_sched_barrier(0);
        __builtin_amdgcn_s_setprio(1);
#pragma unroll
        for (int mf = 0; mf < 4; ++mf)
#pragma unroll
            for (int nf = 0; nf < 4; ++nf)
                acc[mf][nf] = mfma16(aF[mf], bF[nf], acc[mf][nf]);
        __builtin_amdgcn_s_setprio(0);
        asm volatile("s_waitcnt lgkmcnt(0)" ::: "memory");
        __builtin_amdgcn_s_barrier();
        roff = woff;
    }

    float* P = Pp + ((size_t)(ks * 32 + hs) << 16);
#pragma unroll
    for (int mf = 0; mf < 4; ++mf) {
        const int m = mT * 128 + wm * 64 + mf * 16 + g * 4;
#pragma unroll
        for (int nf = 0; nf < 4; ++nf) {
            const int nn = wn * 64 + nf * 16 + cl;
            f32x4 v = acc[mf][nf];
#pragma unroll
            for (int r = 0; r < 4; ++r)
                P[(size_t)(m + r) * 256 + nn] = v[r];
        }
    }
}

// ---- reduce 4 K-splits, cast. sf=0: Kp [bh][k][d]; sf=1: Vpt [bh][d][k] ----
__global__ __launch_bounds__(256) void k_red(const float* __restrict__ Pp,
                                             u16* __restrict__ Kp,
                                             u16* __restrict__ Vpt) {
    const int e = blockIdx.x * 256 + threadIdx.x;
    const int hs = e >> 14;
    const int rem = (e & 16383) * 4;
    float4 sum = {0.f, 0.f, 0.f, 0.f};
#pragma unroll
    for (int ks = 0; ks < 4; ++ks) {
        const float4 v = *(const float4*)(Pp + (((size_t)(ks * 32 + hs)) << 16) + rem);
        sum.x += v.x; sum.y += v.y; sum.z += v.z; sum.w += v.w;
    }
    const int m = rem >> 8, col = rem & 255;
    const int h = hs & 15, sf = hs >> 4;
    ushort4 pk;
    pk.x = f2bf(sum.x); pk.y = f2bf(sum.y);
    pk.z = f2bf(sum.z); pk.w = f2bf(sum.w);
    if (sf == 0) {
        const int bh = (col >> 6) * 16 + h, d0 = col & 63;
        *(ushort4*)(Kp + (size_t)bh * 16384 + m * 64 + d0) = pk;
    } else {
        const int bh = (m >> 6) * 16 + h, d = m & 63;
        *(ushort4*)(Vpt + (size_t)bh * 16384 + d * 256 + col) = pk;
    }
}

// ---------------- fused attention: S^T = Kp@Q^T, softmax, O^T = Vp^T@P ----------------
__global__ __launch_bounds__(256, 1) void k_attn(
    const u16* __restrict__ Q, const u16* __restrict__ Kp,
    const u16* __restrict__ Vpt, u16* __restrict__ AO) {
    __shared__ __align__(16) char sm[65536];
    const int lane = threadIdx.x & 63, wid = threadIdx.x >> 6;
    const int cl = lane & 15, g = lane >> 4;
    const int tT = blockIdx.x, h = blockIdx.y, b = blockIdx.z;
    const int bh = b * 16 + h;
    const int trow0 = b * 4096 + tT * 128 + wid * 32;
    const u16* Qb = Q + (size_t)trow0 * 1024 + h * 64;
    const u16* KpB = Kp + (size_t)bh * (256 * 64);
    const u16* VpB = Vpt + (size_t)bh * (64 * 256);
    char* sP = sm + wid * 16384;

    bf16x8 qF[2][2];
#pragma unroll
    for (int nf = 0; nf < 2; ++nf)
#pragma unroll
        for (int ks = 0; ks < 2; ++ks)
            qF[nf][ks] = *(const bf16x8*)(Qb + (size_t)(nf * 16 + cl) * 1024 + ks * 32 + g * 8);

    const f32x4 fz = {0.f, 0.f, 0.f, 0.f};
    f32x4 Sp[16][2];
#pragma unroll
    for (int mf = 0; mf < 16; ++mf) { Sp[mf][0] = fz; Sp[mf][1] = fz; }

#pragma unroll
    for (int mf = 0; mf < 16; ++mf) {
#pragma unroll
        for (int ks = 0; ks < 2; ++ks) {
            bf16x8 aF = *(const bf16x8*)(KpB + (size_t)(mf * 16 + cl) * 64 + ks * 32 + g * 8);
            Sp[mf][0] = mfma16(aF, qF[0][ks], Sp[mf][0]);
            Sp[mf][1] = mfma16(aF, qF[1][ks], Sp[mf][1]);
        }
    }

    float inv_sum[2];
#pragma unroll
    for (int nf = 0; nf < 2; ++nf) {
        float mx = -1e30f;
#pragma unroll
        for (int mf = 0; mf < 16; ++mf)
#pragma unroll
            for (int r = 0; r < 4; ++r) {
                float x = Sp[mf][nf][r] * 0.125f;
                Sp[mf][nf][r] = x;
                mx = fmaxf(mx, x);
            }
        mx = fmaxf(mx, __shfl_xor(mx, 16));
        mx = fmaxf(mx, __shfl_xor(mx, 32));
        float sum = 0.f;
#pragma unroll
        for (int mf = 0; mf < 16; ++mf)
#pragma unroll
            for (int r = 0; r < 4; ++r) {
                float p = __expf(Sp[mf][nf][r] - mx);
                Sp[mf][nf][r] = p;
                sum += p;
            }
        sum += __shfl_xor(sum, 16);
        sum += __shfl_xor(sum, 32);
        inv_sum[nf] = 1.0f / sum;

        const int tl = nf * 16 + cl;
        const int sw = (tl & 7) << 4;
#pragma unroll
        for (int mf = 0; mf < 16; ++mf) {
            uint2 pk;
            pk.x = (u32)f2bf(Sp[mf][nf][0]) | ((u32)f2bf(Sp[mf][nf][1]) << 16);
            pk.y = (u32)f2bf(Sp[mf][nf][2]) | ((u32)f2bf(Sp[mf][nf][3]) << 16);
            *(uint2*)(sP + ((tl * 512 + (mf * 16 + g * 4) * 2) ^ sw)) = pk;
        }
    }

    f32x4 Oa[4][2];
#pragma unroll
    for (int mf = 0; mf < 4; ++mf) { Oa[mf][0] = fz; Oa[mf][1] = fz; }
#pragma unroll
    for (int ks = 0; ks < 8; ++ks) {
        bf16x8 aF[4];
#pragma unroll
        for (int mf = 0; mf < 4; ++mf)
            aF[mf] = *(const bf16x8*)(VpB + (size_t)(mf * 16 + cl) * 256 + ks * 32 + g * 8);
#pragma unroll
        for (int nf = 0; nf < 2; ++nf) {
            const int tl = nf * 16 + cl;
            const int sw = (tl & 7) << 4;
            bf16x8 bF = *(const bf16x8*)(sP + ((tl * 512 + (ks * 32 + g * 8) * 2) ^ sw));
#pragma unroll
            for (int mf = 0; mf < 4; ++mf)
                Oa[mf][nf] = mfma16(aF[mf], bF, Oa[mf][nf]);
        }
    }

#pragma unroll
    for (int nf = 0; nf < 2; ++nf) {
        const int t = trow0 + nf * 16 + cl;
#pragma unroll
        for (int mf = 0; mf < 4; ++mf) {
            f32x4 v = Oa[mf][nf];
            ushort4 pk;
            pk.x = f2bf(v[0] * inv_sum[nf]); pk.y = f2bf(v[1] * inv_sum[nf]);
            pk.z = f2bf(v[2] * inv_sum[nf]); pk.w = f2bf(v[3] * inv_sum[nf]);
            *(ushort4*)(AO + (size_t)t * 1024 + h * 64 + mf * 16 + g * 4) = pk;
        }
    }
}

extern "C" void kernel_launch(void* const* d_in, const int* in_sizes, int n_in,
                              void* d_out, int out_size, void* d_ws, size_t ws_size,
                              hipStream_t stream) {
    const float* X  = (const float*)d_in[0];
    const float* Wk = (const float*)d_in[1];
    const float* Wb = (const float*)d_in[2];
    const float* E  = (const float*)d_in[3];
    const float* F  = (const float*)d_in[4];
    const float* Ok = (const float*)d_in[5];
    const float* Ob = (const float*)d_in[6];
    float* out = (float*)d_out;
    char* ws = (char*)d_ws;

    u16* Xn  = (u16*)(ws + 0);            // 32MB; reused as Pp (kpvp) then AO (attn)
    u16* Wt  = (u16*)(ws + 33554432);     // 6MB   [3072][1024]
    u16* Ot  = (u16*)(ws + 39845888);     // 2MB   [1024][1024]
    u16* Et  = (u16*)(ws + 41943040);     // 32MB  [16][256][4096]
    u16* Ft  = (u16*)(ws + 75497472);     // 32MB
    u16* Qb  = (u16*)(ws + 109051904);    // 32MB  [16384][1024]
    u16* Kt  = (u16*)(ws + 142606336);    // 32MB  [4][16][64][4096]
    u16* Vt  = (u16*)(ws + 176160768);    // 32MB
    u16* Kp  = (u16*)(ws + 209715200);    // 2MB   [64][256][64]
    u16* Vpt = (u16*)(ws + 211812352);    // 2MB   [64][64][256]
    float* Pp = (float*)(ws + 0);         // 32MB fp32 partials (Xn dead after qkv)
    u16* AO  = Xn;                        // Pp dead after k_red

    k_prep<<<25600, 256, 0, stream>>>(X, Xn, Wk, Wt, Ok, Ot, E, Et, F, Ft);
    k_gemm_qkv<<<768, 512, 0, stream>>>(Xn, Wt, Wb, Qb, Kt, Vt);
    k_gemm_kpvp<<<dim3(2, 32, 4), 512, 0, stream>>>(Et, Ft, Kt, Vt, Pp);
    k_red<<<2048, 256, 0, stream>>>(Pp, Kp, Vpt);
    k_attn<<<dim3(32, 16, 4), 256, 0, stream>>>(Qb, Kp, Vpt, AO);
    k_gemm_out<<<256, 512, 0, stream>>>(AO, Ot, Ob, out);
}